// Round 8
// baseline (89.669 us; speedup 1.0000x reference)
//
#include <hip/hip_runtime.h>
#include <hip/hip_bf16.h>
#include <math.h>

#define KS 3
#define C_IN 64
#define F_OUT 128
#define NPOS 9
#define HH 128
#define WWID 128
#define NB 16

typedef __attribute__((ext_vector_type(8))) short bf16x8;
typedef __attribute__((ext_vector_type(4))) float f32x4;

__device__ __forceinline__ unsigned short f2bf(float f) {
  union { float f; unsigned u; } v; v.f = f;
  unsigned u = v.u;
  return (unsigned short)((u + 0x7FFFu + ((u >> 16) & 1u)) >> 16);  // RNE
}
__device__ __forceinline__ unsigned cvtpk(float lo, float hi) {
  unsigned r;
  asm("v_cvt_pk_bf16_f32 %0, %1, %2" : "=v"(r) : "v"(lo), "v"(hi));
  return r;
}
__device__ __forceinline__ bf16x8 pack8(float4 v0, float4 v1) {
  union { unsigned u[4]; bf16x8 v; } r;
  r.u[0] = cvtpk(v0.x, v0.y); r.u[1] = cvtpk(v0.z, v0.w);
  r.u[2] = cvtpk(v1.x, v1.y); r.u[3] = cvtpk(v1.z, v1.w);
  return r.v;
}

// ---- Kernel 1: AW (bf16 in {-1,0,1}) in ch-sliced swizzled layout.
// Element (p,f,c): ch=c>>5, cg=(c>>3)&3, ps=(cg+((f&15)>>1))&3 ->
// off = ((ch*9+p)*128+f)*32 + ps*8 + (c&7).
// Each ch-slice (73728 B) is one linear LDS copy; the conv kernel's
// ps-swizzled ds_read_b128 is the r5-verified 0-conflict pattern.
__global__ void compute_aw(const float* __restrict__ kern,
                           const float* __restrict__ D,
                           const float* __restrict__ gu,
                           unsigned short* __restrict__ AWsw) {
  int t = blockIdx.x * blockDim.x + threadIdx.x;
  if (t >= F_OUT * C_IN) return;
  int base = t * NPOS;
  float pert[NPOS];
#pragma unroll
  for (int n = 0; n < NPOS; ++n) {
    float u = gu[base + n];
    float g = -0.001f * logf(-logf(u + 1e-20f) + 1e-20f);
    pert[n] = D[base + n] + g;
  }
  unsigned mask = 0;
#pragma unroll
  for (int k = 0; k < 4; ++k) {
    int best = 0; float bv = -INFINITY;
#pragma unroll
    for (int n = 0; n < NPOS; ++n) {
      bool taken = (mask >> n) & 1;
      if (!taken && pert[n] > bv) { bv = pert[n]; best = n; }
    }
    mask |= (1u << best);
  }
#pragma unroll
  for (int n = 0; n < NPOS; ++n) {
    int L = base + n;
    float kv = kern[L];
    float s = (kv > 0.f) ? 1.f : ((kv < 0.f) ? -1.f : 0.f);
    float v = ((mask >> n) & 1) ? s : 0.f;
    int f = L & (F_OUT - 1);
    int r = L >> 7;
    int c = r & (C_IN - 1);
    int p = r >> 6;
    int ch = c >> 5;
    int cg = (c >> 3) & 3;
    int ps = (cg + ((f & 15) >> 1)) & 3;
    int off = ((ch * NPOS + p) * F_OUT + f) * 32 + ps * 8 + (c & 7);
    AWsw[off] = f2bf(v);
  }
}

// ---- Kernel 2: fused implicit-GEMM conv, both operands LDS-resident.
// 1024 thr / 16 waves; block = 4 output rows (M=512) x F=128; wave tile
// 64x64 (8 M-slots x 2 f-halves); 2 phases (ch-halves), 4 barriers total.
// As: 6 input rows x 65 px-pairs x 32 ch, pair-row swizzle
//     chunk = (((pp&1)<<2)|cg) ^ ((pp>>1)&7)  (2-way max on read & write).
// Bs: full 9-pos x 128-f ch-slice (72 KiB), linear copy from AWsw.
__global__ __launch_bounds__(1024, 4)
void conv3(const float* __restrict__ x,
           const unsigned short* __restrict__ AWsw,
           const float* __restrict__ bias,
           float* __restrict__ out) {
  __shared__ __align__(16) unsigned short As[6 * 65 * 64];     // 49920 B
  __shared__ __align__(16) unsigned short Bs[NPOS * F_OUT * 32]; // 73728 B

  int tid = threadIdx.x;
  int lane = tid & 63, wave = tid >> 6;
  int lr = lane & 15, lg = lane >> 4;

  int bid = blockIdx.x;
  int wg = (bid & 7) * 64 + (bid >> 3);   // XCD-contiguous (512 % 8 == 0)
  int n = wg >> 5;
  int h0 = (wg & 31) * 4;

  int mslot = wave & 7, fh = wave >> 3;
  int ro = mslot >> 1;          // output row within strip (0..3)
  int px0 = (mslot & 1) * 64;   // w-half
  int f0 = fh * 64;             // f-half

  const float* xim = x + ((long long)n * HH) * WWID * C_IN;

  // A ch-slice stage: 3072 chunks = (r 0..5) x (px 0..127) x (cg 0..3)
#define STAGE_A(CH)                                                          \
  {                                                                          \
    _Pragma("unroll")                                                        \
    for (int t = 0; t < 3; ++t) {                                            \
      int ci = t * 1024 + tid;                                               \
      int r = ci >> 9, px = (ci >> 2) & 127, cg = ci & 3;                    \
      int hh = h0 - 1 + r;                                                   \
      if ((unsigned)hh < (unsigned)HH) {                                     \
        const float* sp = xim + (long long)hh * (WWID * C_IN) + px * C_IN +  \
                          (CH) * 32 + cg * 8;                                \
        float4 v0 = *reinterpret_cast<const float4*>(sp);                    \
        float4 v1 = *reinterpret_cast<const float4*>(sp + 4);                \
        int pp = px + 1;                                                     \
        int chk = (((pp & 1) << 2) | cg) ^ ((pp >> 1) & 7);                  \
        *reinterpret_cast<bf16x8*>((char*)As + r * 8320 + (pp >> 1) * 128 +  \
                                   chk * 16) = pack8(v0, v1);                \
      }                                                                      \
    }                                                                        \
  }
  // B ch-slice stage: 4608 chunks of 16 B, linear.
#define STAGE_B(CH)                                                          \
  {                                                                          \
    const unsigned short* src = AWsw + (CH) * (NPOS * F_OUT * 32);           \
    _Pragma("unroll")                                                        \
    for (int t = 0; t < 5; ++t) {                                            \
      int ci = t * 1024 + tid;                                               \
      if (ci < 4608)                                                         \
        *reinterpret_cast<bf16x8*>(Bs + ci * 8) =                            \
            *reinterpret_cast<const bf16x8*>(src + ci * 8);                  \
    }                                                                        \
  }
  // one ch-phase: 9 positions x (4 b + 4 a ds_read_b128 + 16 MFMA)
#define COMPUTE()                                                            \
  {                                                                          \
    _Pragma("unroll")                                                        \
    for (int p = 0; p < NPOS; ++p) {                                         \
      const int i = p / 3, j = p % 3;                                        \
      const char* bp = (const char*)Bs + p * 8192 + (f0 + lr) * 64 +         \
                       (((lg + (lr >> 1)) & 3) << 4);                        \
      bf16x8 b[4];                                                           \
      _Pragma("unroll")                                                      \
      for (int nf = 0; nf < 4; ++nf)                                         \
        b[nf] = *reinterpret_cast<const bf16x8*>(bp + nf * 1024);            \
      bf16x8 a[4];                                                           \
      _Pragma("unroll")                                                      \
      for (int mfi = 0; mfi < 4; ++mfi) {                                    \
        int pp = px0 + mfi * 16 + lr + j;                                    \
        int chk = (((pp & 1) << 2) | lg) ^ ((pp >> 1) & 7);                  \
        a[mfi] = *reinterpret_cast<const bf16x8*>(                           \
            (const char*)As + (ro + i) * 8320 + (pp >> 1) * 128 + chk * 16); \
      }                                                                      \
      _Pragma("unroll")                                                      \
      for (int mfi = 0; mfi < 4; ++mfi)                                      \
        _Pragma("unroll")                                                    \
        for (int nf = 0; nf < 4; ++nf)                                       \
          acc[mfi][nf] = __builtin_amdgcn_mfma_f32_16x16x32_bf16(            \
              a[mfi], b[nf], acc[mfi][nf], 0, 0, 0);                         \
    }                                                                        \
  }

  // memset As (covers px pads 0/129 and out-of-image rows)
  bf16x8 z = {};
#pragma unroll
  for (int t = 0; t < 4; ++t) {
    int ci = t * 1024 + tid;
    if (ci < 3120) *reinterpret_cast<bf16x8*>(As + ci * 8) = z;
  }
  __syncthreads();

  f32x4 acc[4][4] = {};

  STAGE_A(0)
  STAGE_B(0)
  __syncthreads();
  COMPUTE()                      // ch 0, all 9 positions
  __syncthreads();
  STAGE_A(1)
  STAGE_B(1)
  __syncthreads();
  COMPUTE()                      // ch 1, all 9 positions

  // ---- epilogue: D col=lr (f), row=lg*4+rr (w); nf innermost -> 4x64 B.
  float bi[4];
#pragma unroll
  for (int nf = 0; nf < 4; ++nf) bi[nf] = bias[f0 + nf * 16 + lr];
  int ho = h0 + ro;
  long long ob = ((long long)(n * HH + ho)) * WWID * F_OUT + f0 + lr;
#pragma unroll
  for (int mfi = 0; mfi < 4; ++mfi) {
#pragma unroll
    for (int rr = 0; rr < 4; ++rr) {
      int w = px0 + mfi * 16 + lg * 4 + rr;
      float* op = out + ob + (long long)w * F_OUT;
#pragma unroll
      for (int nf = 0; nf < 4; ++nf)
        op[nf * 16] = fmaxf(acc[mfi][nf][rr] + bi[nf], 0.f);
    }
  }
#undef STAGE_A
#undef STAGE_B
#undef COMPUTE
}

extern "C" void kernel_launch(void* const* d_in, const int* in_sizes, int n_in,
                              void* d_out, int out_size, void* d_ws, size_t ws_size,
                              hipStream_t stream) {
  const float* x    = (const float*)d_in[0];  // (16,128,128,64)
  const float* kern = (const float*)d_in[1];  // (3,3,64,128)
  const float* bias = (const float*)d_in[2];  // (128,)
  const float* D    = (const float*)d_in[3];  // (3,3,64,128)
  const float* gu   = (const float*)d_in[4];  // (1,128,64,9)

  unsigned short* AWsw = (unsigned short*)d_ws;  // 2 slices x 36864 = 144 KiB

  compute_aw<<<(F_OUT * C_IN + 255) / 256, 256, 0, stream>>>(kern, D, gu, AWsw);

  conv3<<<NB * (HH / 4), 1024, 0, stream>>>(x, AWsw, bias, (float*)d_out);
}

// Round 9
// 82.471 us; speedup vs baseline: 1.0873x; 1.0873x over previous
//
#include <hip/hip_runtime.h>
#include <hip/hip_bf16.h>
#include <math.h>

#define KS 3
#define C_IN 64
#define F_OUT 128
#define NPOS 9
#define HH 128
#define WWID 128
#define NB 16

typedef __attribute__((ext_vector_type(8))) short bf16x8;
typedef __attribute__((ext_vector_type(4))) float f32x4;

__device__ __forceinline__ unsigned short f2bf(float f) {
  union { float f; unsigned u; } v; v.f = f;
  unsigned u = v.u;
  return (unsigned short)((u + 0x7FFFu + ((u >> 16) & 1u)) >> 16);  // RNE
}
__device__ __forceinline__ unsigned cvtpk(float lo, float hi) {
  unsigned r;
  asm("v_cvt_pk_bf16_f32 %0, %1, %2" : "=v"(r) : "v"(lo), "v"(hi));
  return r;
}
__device__ __forceinline__ bf16x8 pack8(float4 v0, float4 v1) {
  union { unsigned u[4]; bf16x8 v; } r;
  r.u[0] = cvtpk(v0.x, v0.y); r.u[1] = cvtpk(v0.z, v0.w);
  r.u[2] = cvtpk(v1.x, v1.y); r.u[3] = cvtpk(v1.z, v1.w);
  return r.v;
}
__device__ __forceinline__ void gload16(const void* g, void* l) {
  __builtin_amdgcn_global_load_lds(
      (const __attribute__((address_space(1))) unsigned int*)g,
      (__attribute__((address_space(3))) unsigned int*)l, 16, 0, 0);
}

// ---- Kernel 1: AW (bf16 in {-1,0,1}), ch-sliced swizzled layout (r5-verified
// 0-conflict B pattern). Element (p,f,c): ch=c>>5, cg=(c>>3)&3,
// ps=(cg+((f&15)>>1))&3 -> elem off = ((ch*9+p)*128+f)*32 + ps*8 + (c&7).
// Each ch-slice (73728 B) is LINEAR for the conv kernel's global_load_lds.
__global__ void compute_aw(const float* __restrict__ kern,
                           const float* __restrict__ D,
                           const float* __restrict__ gu,
                           unsigned short* __restrict__ AWsw) {
  int t = blockIdx.x * blockDim.x + threadIdx.x;
  if (t >= F_OUT * C_IN) return;
  int base = t * NPOS;
  float pert[NPOS];
#pragma unroll
  for (int n = 0; n < NPOS; ++n) {
    float u = gu[base + n];
    float g = -0.001f * logf(-logf(u + 1e-20f) + 1e-20f);
    pert[n] = D[base + n] + g;
  }
  unsigned mask = 0;
#pragma unroll
  for (int k = 0; k < 4; ++k) {
    int best = 0; float bv = -INFINITY;
#pragma unroll
    for (int n = 0; n < NPOS; ++n) {
      bool taken = (mask >> n) & 1;
      if (!taken && pert[n] > bv) { bv = pert[n]; best = n; }
    }
    mask |= (1u << best);
  }
#pragma unroll
  for (int n = 0; n < NPOS; ++n) {
    int L = base + n;
    float kv = kern[L];
    float s = (kv > 0.f) ? 1.f : ((kv < 0.f) ? -1.f : 0.f);
    float v = ((mask >> n) & 1) ? s : 0.f;
    int f = L & (F_OUT - 1);
    int r = L >> 7;
    int c = r & (C_IN - 1);
    int p = r >> 6;
    int ch = c >> 5;
    int cg = (c >> 3) & 3;
    int ps = (cg + ((f & 15) >> 1)) & 3;
    int off = ((ch * NPOS + p) * F_OUT + f) * 32 + ps * 8 + (c & 7);
    AWsw[off] = f2bf(v);
  }
}

// ---- Kernel 2: x fp32 -> bf16 in the conv kernel's exact LDS image:
// per (n,h,ch-half): 8192 B = padded-px pair-row swizzle. px p -> pp=p+1,
// pair=pp>>1, b=pp&1, chunk=((b<<2)|cg2)^(pair&7), byte = pair*128+chunk*16-64.
// Conv staging is then a LINEAR global_load_lds copy (rule 21: swizzle in
// source + read, LDS linear).
__global__ void convert_x(const float* __restrict__ x,
                          unsigned short* __restrict__ xsw) {
  int t = blockIdx.x * 256 + threadIdx.x;     // one 16 B chunk each
  int cg2 = t & 3;
  int px = (t >> 2) & 127;
  int half = (t >> 9) & 1;
  int row = t >> 10;                          // n*128+h
  const float* sp = x + ((size_t)row * 128 + px) * C_IN + half * 32 + cg2 * 8;
  float4 v0 = *reinterpret_cast<const float4*>(sp);
  float4 v1 = *reinterpret_cast<const float4*>(sp + 4);
  int pp = px + 1;
  int pair = pp >> 1, b = pp & 1;
  int chunk = ((b << 2) | cg2) ^ (pair & 7);
  size_t off = (size_t)(row * 2 + half) * 8192 + pair * 128 + chunk * 16 - 64;
  *reinterpret_cast<bf16x8*>((char*)xsw + off) = pack8(v0, v1);
}

// ---- Kernel 3: fused implicit-GEMM conv. 512 thr / 8 waves; block = 4 output
// rows (M=512) x F=128; wave tile 64(M) x 128(N): mf=4, nf=8, acc=128 VGPR.
// ALL staging via global_load_lds width-16 (no VALU, no ds_write).
// As: 6 rows x 65 pair-rows x 128 B (ch-half slice); Bs: 9x128x32 ch-slice.
// 2 ch-phases, 4 barriers.
__global__ __launch_bounds__(512, 2)
void conv4(const unsigned short* __restrict__ xsw,
           const unsigned short* __restrict__ AWsw,
           const float* __restrict__ bias,
           float* __restrict__ out) {
  __shared__ __align__(16) unsigned short As[6 * 65 * 64];       // 49920 B
  __shared__ __align__(16) unsigned short Bs[NPOS * F_OUT * 32]; // 73728 B

  int tid = threadIdx.x;
  int lane = tid & 63, wave = tid >> 6;
  int lr = lane & 15, lg = lane >> 4;

  int bid = blockIdx.x;
  int wg = (bid & 7) * 64 + (bid >> 3);   // XCD-contiguous (512 % 8 == 0)
  int n = wg >> 5;
  int h0 = (wg & 31) * 4;

  int ro = wave >> 1;          // output row within strip (0..3)
  int m0 = (wave & 1) * 64;    // px half

  // A stage: 48 wave-issues (6 rows x 8 KiB), 6 per wave; B: 72, 9 per wave.
#define STAGE(CH)                                                            \
  {                                                                          \
    _Pragma("unroll")                                                        \
    for (int k = 0; k < 6; ++k) {                                            \
      int idx = wave * 6 + k;                                                \
      int r = idx >> 3, q8 = idx & 7;                                        \
      int hh = h0 - 1 + r;                                                   \
      if ((unsigned)hh < (unsigned)HH) {                                     \
        const unsigned short* src = xsw +                                    \
            ((size_t)((n * HH + hh) * 2 + (CH))) * 4096 + q8 * 512 +         \
            lane * 8;                                                        \
        gload16(src, (char*)As + r * 8320 + 64 + q8 * 1024);                 \
      }                                                                      \
    }                                                                        \
    _Pragma("unroll")                                                        \
    for (int k = 0; k < 9; ++k) {                                            \
      int ci = wave * 9 + k;                                                 \
      const unsigned short* src =                                            \
          AWsw + (CH) * (NPOS * F_OUT * 32) + ci * 512 + lane * 8;           \
      gload16(src, (char*)Bs + ci * 1024);                                   \
    }                                                                        \
  }

  // one ch-phase: 9 pos x (8 b + 4 a ds_read_b128 + 32 MFMA)
#define COMPUTE()                                                            \
  {                                                                          \
    _Pragma("unroll")                                                        \
    for (int p = 0; p < NPOS; ++p) {                                         \
      const int i = p / 3, j = p % 3;                                        \
      const char* bp = (const char*)Bs + p * 8192 + lr * 64 +                \
                       (((lg + (lr >> 1)) & 3) << 4);                        \
      bf16x8 b[8];                                                           \
      _Pragma("unroll")                                                      \
      for (int nf = 0; nf < 8; ++nf)                                         \
        b[nf] = *reinterpret_cast<const bf16x8*>(bp + nf * 1024);            \
      bf16x8 a[4];                                                           \
      _Pragma("unroll")                                                      \
      for (int mfi = 0; mfi < 4; ++mfi) {                                    \
        int pp = m0 + mfi * 16 + lr + j;                                     \
        int chunk = (((pp & 1) << 2) | lg) ^ ((pp >> 1) & 7);                \
        a[mfi] = *reinterpret_cast<const bf16x8*>(                           \
            (const char*)As + (ro + i) * 8320 + (pp >> 1) * 128 +            \
            chunk * 16);                                                     \
      }                                                                      \
      _Pragma("unroll")                                                      \
      for (int mfi = 0; mfi < 4; ++mfi)                                      \
        _Pragma("unroll")                                                    \
        for (int nf = 0; nf < 8; ++nf)                                       \
          acc[mfi][nf] = __builtin_amdgcn_mfma_f32_16x16x32_bf16(            \
              a[mfi], b[nf], acc[mfi][nf], 0, 0, 0);                         \
    }                                                                        \
  }

  // memset pads: edge blocks zero all of As; interior only the 2x64 B pads.
  bf16x8 z = {};
  if (h0 == 0 || h0 == 124) {
    for (int t = tid; t < 3120; t += 512)
      *reinterpret_cast<bf16x8*>(As + t * 8) = z;
  } else if (tid < 48) {
    int r = tid >> 3, c8 = tid & 7;
    int off = r * 8320 + ((c8 < 4) ? c8 * 16 : 8192 + c8 * 16);
    *reinterpret_cast<bf16x8*>((char*)As + off) = z;
  }

  f32x4 acc[4][8] = {};

  STAGE(0)
  __syncthreads();             // drains vmcnt (gload_lds) + lgkm (memset)
  COMPUTE()                    // ch 0
  __syncthreads();
  STAGE(1)
  __syncthreads();
  COMPUTE()                    // ch 1

  // epilogue: lane (lr,lg) -> f = nf*16+lr, w = m0+mfi*16+lg*4+r4.
  // nf-inner: wave covers full 512 B f-line per w -> full-line HBM writes.
  float bi[8];
#pragma unroll
  for (int nf = 0; nf < 8; ++nf) bi[nf] = bias[nf * 16 + lr];
  int ho = h0 + ro;
  long long ob = ((long long)(n * HH + ho)) * WWID * F_OUT + lr;
#pragma unroll
  for (int mfi = 0; mfi < 4; ++mfi) {
#pragma unroll
    for (int r4 = 0; r4 < 4; ++r4) {
      int w = m0 + mfi * 16 + lg * 4 + r4;
      float* op = out + ob + (long long)w * F_OUT;
#pragma unroll
      for (int nf = 0; nf < 8; ++nf)
        op[nf * 16] = fmaxf(acc[mfi][nf][r4] + bi[nf], 0.f);
    }
  }
#undef STAGE
#undef COMPUTE
}

extern "C" void kernel_launch(void* const* d_in, const int* in_sizes, int n_in,
                              void* d_out, int out_size, void* d_ws, size_t ws_size,
                              hipStream_t stream) {
  const float* x    = (const float*)d_in[0];  // (16,128,128,64)
  const float* kern = (const float*)d_in[1];  // (3,3,64,128)
  const float* bias = (const float*)d_in[2];  // (128,)
  const float* D    = (const float*)d_in[3];  // (3,3,64,128)
  const float* gu   = (const float*)d_in[4];  // (1,128,64,9)

  const size_t xbytes = (size_t)NB * HH * WWID * C_IN * 2;   // 32 MiB
  unsigned short* xsw  = (unsigned short*)d_ws;
  unsigned short* AWsw = (unsigned short*)((char*)d_ws + xbytes);  // 144 KiB

  compute_aw<<<(F_OUT * C_IN + 255) / 256, 256, 0, stream>>>(kern, D, gu, AWsw);

  int nchunks = NB * HH * WWID * 8;          // 2,097,152 16 B-chunks
  convert_x<<<nchunks / 256, 256, 0, stream>>>(x, xsw);

  conv4<<<NB * (HH / 4), 512, 0, stream>>>(xsw, AWsw, bias, (float*)d_out);
}

// Round 10
// 59.459 us; speedup vs baseline: 1.5081x; 1.3870x over previous
//
#include <hip/hip_runtime.h>
#include <hip/hip_bf16.h>
#include <math.h>

#define KS 3
#define C_IN 64
#define F_OUT 128
#define NPOS 9
#define HH 128
#define WWID 128
#define NB 16

typedef __attribute__((ext_vector_type(8))) short bf16x8;
typedef __attribute__((ext_vector_type(4))) float f32x4;

__device__ __forceinline__ unsigned short f2bf(float f) {
  union { float f; unsigned u; } v; v.f = f;
  unsigned u = v.u;
  return (unsigned short)((u + 0x7FFFu + ((u >> 16) & 1u)) >> 16);  // RNE
}
__device__ __forceinline__ unsigned cvtpk(float lo, float hi) {
  unsigned r;
  asm("v_cvt_pk_bf16_f32 %0, %1, %2" : "=v"(r) : "v"(lo), "v"(hi));
  return r;
}
__device__ __forceinline__ bf16x8 pack8(float4 v0, float4 v1) {
  union { unsigned u[4]; bf16x8 v; } r;
  r.u[0] = cvtpk(v0.x, v0.y); r.u[1] = cvtpk(v0.z, v0.w);
  r.u[2] = cvtpk(v1.x, v1.y); r.u[3] = cvtpk(v1.z, v1.w);
  return r.v;
}
__device__ __forceinline__ void gload16(const void* g, void* l) {
  __builtin_amdgcn_global_load_lds(
      (const __attribute__((address_space(1))) unsigned int*)g,
      (__attribute__((address_space(3))) unsigned int*)l, 16, 0, 0);
}

// ---- Kernel 1: AW (bf16 in {-1,0,1}) sliced by kernel-row i (= p/3):
// slice s holds positions 3s..3s+2, all 128 f, all 64 ch (48 KiB each).
// Element (p,f,c): pl=p%3, g=c>>3, slot=g^(f&7) ->
// elem off = s*24576 + ((pl*128+f)*8 + slot)*8 + (c&7).
// Slice is LINEAR for gload_lds / reg-copy; conv's slot-swizzled
// ds_read_b128 (b-read: slot=(ch*4+lg)^(lr&7)) is uniform-8 = bank floor.
__global__ void compute_aw(const float* __restrict__ kern,
                           const float* __restrict__ D,
                           const float* __restrict__ gu,
                           unsigned short* __restrict__ AWsw) {
  int t = blockIdx.x * blockDim.x + threadIdx.x;
  if (t >= F_OUT * C_IN) return;
  int base = t * NPOS;
  float pert[NPOS];
#pragma unroll
  for (int n = 0; n < NPOS; ++n) {
    float u = gu[base + n];
    float g = -0.001f * logf(-logf(u + 1e-20f) + 1e-20f);
    pert[n] = D[base + n] + g;
  }
  unsigned mask = 0;
#pragma unroll
  for (int k = 0; k < 4; ++k) {
    int best = 0; float bv = -INFINITY;
#pragma unroll
    for (int n = 0; n < NPOS; ++n) {
      bool taken = (mask >> n) & 1;
      if (!taken && pert[n] > bv) { bv = pert[n]; best = n; }
    }
    mask |= (1u << best);
  }
#pragma unroll
  for (int n = 0; n < NPOS; ++n) {
    int L = base + n;
    float kv = kern[L];
    float sg = (kv > 0.f) ? 1.f : ((kv < 0.f) ? -1.f : 0.f);
    float v = ((mask >> n) & 1) ? sg : 0.f;
    int f = L & (F_OUT - 1);
    int r = L >> 7;
    int c = r & (C_IN - 1);
    int p = r >> 6;
    int s = p / 3, pl = p % 3;
    int g = c >> 3;
    int slot = g ^ (f & 7);
    int off = s * 24576 + ((pl * F_OUT + f) * 8 + slot) * 8 + (c & 7);
    AWsw[off] = f2bf(v);
  }
}

// ---- Kernel 2: fused implicit-GEMM conv. 512 thr / 8 waves; block = 4
// output rows (M=512) x F=128; wave tile 64(M) x 128(N): mf=4, nf=8.
// As: 6 rows x 130 px x 64 ch bf16 (99.84 KiB), staged ONCE from fp32 x
//     (cvt_pk + swizzled ds_write, r6-verified pattern slot=c8^(pp&7)).
// Bs: kernel-row slice (3 pos x 128 f x 64 ch, 48 KiB). B0 via gload_lds
//     issued before A-stage (drain hides under stage); B1/B2 via T14
//     reg-prefetch at phase start. 3 phases x 192 MFMA/wave, 6 barriers.
__global__ __launch_bounds__(512, 2)
void conv5(const float* __restrict__ x,
           const unsigned short* __restrict__ AWsw,
           const float* __restrict__ bias,
           float* __restrict__ out) {
  __shared__ __align__(16) unsigned short As[6 * 130 * 64];  // 99840 B
  __shared__ __align__(16) unsigned short Bs[3 * F_OUT * 64]; // 49152 B

  int tid = threadIdx.x;
  int lane = tid & 63, wave = tid >> 6;
  int lr = lane & 15, lg = lane >> 4;

  int bid = blockIdx.x;
  int wg = (bid & 7) * 64 + (bid >> 3);   // XCD-contiguous (512 % 8 == 0)
  int n = wg >> 5;
  int h0 = (wg & 31) * 4;

  int ro = wave >> 1;          // output row within strip (0..3)
  int m0 = (wave & 1) * 64;    // px half

  // ---- memset: edge blocks zero all of As; interior only the pp=0/129 pads.
  bf16x8 z = {};
  if (h0 == 0 || h0 == 124) {
    for (int t = tid; t < 6240; t += 512)
      *reinterpret_cast<bf16x8*>(As + t * 8) = z;
  } else if (tid < 96) {
    int r = tid >> 4, k = tid & 15;
    int pp = (k >> 3) ? 129 : 0, c8 = k & 7;
    *reinterpret_cast<bf16x8*>((char*)As + r * 16640 + pp * 128 +
                               ((c8 ^ (pp & 7)) << 4)) = z;
  }
  __syncthreads();

  // ---- B0 via gload_lds (48 wave-issues; drain hides under A-stage VALU)
#pragma unroll
  for (int k = 0; k < 6; ++k) {
    int wi = wave * 6 + k;
    gload16(AWsw + wi * 512 + lane * 8, (char*)Bs + wi * 1024);
  }

  // ---- A-stage: 6144 chunks = (r 0..5) x (px 0..127) x (c8 0..7), 12/thread
  const float* xim = x + ((long long)n * HH) * WWID * C_IN;
#pragma unroll
  for (int t = 0; t < 12; ++t) {
    int cid = t * 512 + tid;
    int r = cid >> 10, rem = cid & 1023;
    int px = rem >> 3, c8 = rem & 7;
    int hh = h0 - 1 + r;
    if ((unsigned)hh < (unsigned)HH) {
      const float* sp = xim + (long long)hh * (WWID * C_IN) + px * C_IN + c8 * 8;
      float4 v0 = *reinterpret_cast<const float4*>(sp);
      float4 v1 = *reinterpret_cast<const float4*>(sp + 4);
      int pp = px + 1;
      *reinterpret_cast<bf16x8*>((char*)As + r * 16640 + pp * 128 +
                                 ((c8 ^ (pp & 7)) << 4)) = pack8(v0, v1);
    }
  }
  __syncthreads();

  f32x4 acc[4][8] = {};
  bf16x8 pre[6];

#define PREFETCH(SN)                                                         \
  _Pragma("unroll")                                                          \
  for (int k = 0; k < 6; ++k)                                                \
    pre[k] = *reinterpret_cast<const bf16x8*>(                               \
        AWsw + (SN) * 24576 + (k * 512 + tid) * 8);

#define BWRITE()                                                             \
  _Pragma("unroll")                                                          \
  for (int k = 0; k < 6; ++k)                                                \
    *reinterpret_cast<bf16x8*>(Bs + (k * 512 + tid) * 8) = pre[k];

  // one slice-phase: 3 positions (j=pl) x 2 ch x (8 b + 4 a reads + 32 MFMA)
#define COMPUTE(S)                                                           \
  __builtin_amdgcn_s_setprio(1);                                             \
  _Pragma("unroll")                                                          \
  for (int pl = 0; pl < 3; ++pl) {                                           \
    _Pragma("unroll")                                                        \
    for (int ch = 0; ch < 2; ++ch) {                                         \
      bf16x8 b[8];                                                           \
      _Pragma("unroll")                                                      \
      for (int nf = 0; nf < 8; ++nf)                                         \
        b[nf] = *reinterpret_cast<const bf16x8*>(                            \
            (const char*)Bs + pl * 16384 + nf * 2048 + lr * 128 +            \
            (((ch * 4 + lg) ^ (lr & 7)) << 4));                              \
      bf16x8 a[4];                                                           \
      _Pragma("unroll")                                                      \
      for (int mfi = 0; mfi < 4; ++mfi) {                                    \
        int pxb = m0 + mfi * 16 + lr + pl;                                   \
        a[mfi] = *reinterpret_cast<const bf16x8*>(                           \
            (const char*)As + (ro + (S)) * 16640 + pxb * 128 +               \
            (((ch * 4 + lg) ^ (pxb & 7)) << 4));                             \
      }                                                                      \
      _Pragma("unroll")                                                      \
      for (int mfi = 0; mfi < 4; ++mfi)                                      \
        _Pragma("unroll")                                                    \
        for (int nf = 0; nf < 8; ++nf)                                       \
          acc[mfi][nf] = __builtin_amdgcn_mfma_f32_16x16x32_bf16(            \
              a[mfi], b[nf], acc[mfi][nf], 0, 0, 0);                         \
    }                                                                        \
  }                                                                          \
  __builtin_amdgcn_s_setprio(0);

  PREFETCH(1)
  COMPUTE(0)
  __syncthreads();
  BWRITE()
  __syncthreads();
  PREFETCH(2)
  COMPUTE(1)
  __syncthreads();
  BWRITE()
  __syncthreads();
  COMPUTE(2)

  // ---- epilogue: f = nf*16+lr, w = m0+mfi*16+lg*4+r4; nf-inner stores.
  float bi[8];
#pragma unroll
  for (int nf = 0; nf < 8; ++nf) bi[nf] = bias[nf * 16 + lr];
  int ho = h0 + ro;
  long long ob = ((long long)(n * HH + ho)) * WWID * F_OUT + lr;
#pragma unroll
  for (int mfi = 0; mfi < 4; ++mfi) {
#pragma unroll
    for (int r4 = 0; r4 < 4; ++r4) {
      int w = m0 + mfi * 16 + lg * 4 + r4;
      float* op = out + ob + (long long)w * F_OUT;
#pragma unroll
      for (int nf = 0; nf < 8; ++nf)
        op[nf * 16] = fmaxf(acc[mfi][nf][r4] + bi[nf], 0.f);
    }
  }
#undef PREFETCH
#undef BWRITE
#undef COMPUTE
}

extern "C" void kernel_launch(void* const* d_in, const int* in_sizes, int n_in,
                              void* d_out, int out_size, void* d_ws, size_t ws_size,
                              hipStream_t stream) {
  const float* x    = (const float*)d_in[0];  // (16,128,128,64)
  const float* kern = (const float*)d_in[1];  // (3,3,64,128)
  const float* bias = (const float*)d_in[2];  // (128,)
  const float* D    = (const float*)d_in[3];  // (3,3,64,128)
  const float* gu   = (const float*)d_in[4];  // (1,128,64,9)

  unsigned short* AWsw = (unsigned short*)d_ws;  // 3 slices x 48 KiB = 144 KiB

  compute_aw<<<(F_OUT * C_IN + 255) / 256, 256, 0, stream>>>(kern, D, gu, AWsw);

  conv5<<<NB * (HH / 4), 512, 0, stream>>>(x, AWsw, bias, (float*)d_out);
}

// Round 11
// 57.221 us; speedup vs baseline: 1.5671x; 1.0391x over previous
//
#include <hip/hip_runtime.h>
#include <hip/hip_bf16.h>
#include <math.h>

#define KS 3
#define C_IN 64
#define F_OUT 128
#define NPOS 9
#define HH 128
#define WWID 128
#define NB 16

typedef __attribute__((ext_vector_type(8))) short bf16x8;
typedef __attribute__((ext_vector_type(4))) float f32x4;

__device__ __forceinline__ unsigned short f2bf(float f) {
  union { float f; unsigned u; } v; v.f = f;
  unsigned u = v.u;
  return (unsigned short)((u + 0x7FFFu + ((u >> 16) & 1u)) >> 16);  // RNE
}
__device__ __forceinline__ unsigned cvtpk(float lo, float hi) {
  unsigned r;
  asm("v_cvt_pk_bf16_f32 %0, %1, %2" : "=v"(r) : "v"(lo), "v"(hi));
  return r;
}
__device__ __forceinline__ bf16x8 pack8(float4 v0, float4 v1) {
  union { unsigned u[4]; bf16x8 v; } r;
  r.u[0] = cvtpk(v0.x, v0.y); r.u[1] = cvtpk(v0.z, v0.w);
  r.u[2] = cvtpk(v1.x, v1.y); r.u[3] = cvtpk(v1.z, v1.w);
  return r.v;
}
__device__ __forceinline__ void gload16(const void* g, void* l) {
  __builtin_amdgcn_global_load_lds(
      (const __attribute__((address_space(1))) unsigned int*)g,
      (__attribute__((address_space(3))) unsigned int*)l, 16, 0, 0);
}

// ---- Kernel 1: AW (bf16 in {-1,0,1}) sliced by kernel-row i (= p/3):
// slice s holds positions 3s..3s+2, all 128 f, all 64 ch (48 KiB each).
// Element (p,f,c): pl=p%3, g=c>>3, slot=g^(f&7) ->
// elem off = s*24576 + ((pl*128+f)*8 + slot)*8 + (c&7).  (r10-verified)
__global__ void compute_aw(const float* __restrict__ kern,
                           const float* __restrict__ D,
                           const float* __restrict__ gu,
                           unsigned short* __restrict__ AWsw) {
  int t = blockIdx.x * blockDim.x + threadIdx.x;
  if (t >= F_OUT * C_IN) return;
  int base = t * NPOS;
  float pert[NPOS];
#pragma unroll
  for (int n = 0; n < NPOS; ++n) {
    float u = gu[base + n];
    float g = -0.001f * logf(-logf(u + 1e-20f) + 1e-20f);
    pert[n] = D[base + n] + g;
  }
  unsigned mask = 0;
#pragma unroll
  for (int k = 0; k < 4; ++k) {
    int best = 0; float bv = -INFINITY;
#pragma unroll
    for (int n = 0; n < NPOS; ++n) {
      bool taken = (mask >> n) & 1;
      if (!taken && pert[n] > bv) { bv = pert[n]; best = n; }
    }
    mask |= (1u << best);
  }
#pragma unroll
  for (int n = 0; n < NPOS; ++n) {
    int L = base + n;
    float kv = kern[L];
    float sg = (kv > 0.f) ? 1.f : ((kv < 0.f) ? -1.f : 0.f);
    float v = ((mask >> n) & 1) ? sg : 0.f;
    int f = L & (F_OUT - 1);
    int r = L >> 7;
    int c = r & (C_IN - 1);
    int p = r >> 6;
    int s = p / 3, pl = p % 3;
    int g = c >> 3;
    int slot = g ^ (f & 7);
    int off = s * 24576 + ((pl * F_OUT + f) * 8 + slot) * 8 + (c & 7);
    AWsw[off] = f2bf(v);
  }
}

// ---- Kernel 2: fused implicit-GEMM conv — r10 structure, re-cut to 1024 thr
// / 16 waves, wave tile 64(M) x 64(N) (mf=4, nf=4, acc=64) -> 4 waves/SIMD.
// Identical 3-phase B-slicing, barriers, and verified swizzles.
__global__ __launch_bounds__(1024, 4)
void conv6(const float* __restrict__ x,
           const unsigned short* __restrict__ AWsw,
           const float* __restrict__ bias,
           float* __restrict__ out) {
  __shared__ __align__(16) unsigned short As[6 * 130 * 64];   // 99840 B
  __shared__ __align__(16) unsigned short Bs[3 * F_OUT * 64]; // 49152 B

  int tid = threadIdx.x;
  int lane = tid & 63, wave = tid >> 6;
  int lr = lane & 15, lg = lane >> 4;

  int bid = blockIdx.x;
  int wg = (bid & 7) * 64 + (bid >> 3);   // XCD-contiguous (512 % 8 == 0)
  int n = wg >> 5;
  int h0 = (wg & 31) * 4;

  int ro = wave >> 2;                 // output row within strip (0..3)
  int m0 = ((wave >> 1) & 1) * 64;    // px half
  int f0 = (wave & 1) * 64;           // f half

  // ---- memset: edge blocks zero all of As; interior only pp=0/129 pads.
  bf16x8 z = {};
  if (h0 == 0 || h0 == 124) {
    for (int t = tid; t < 6240; t += 1024)
      *reinterpret_cast<bf16x8*>(As + t * 8) = z;
  } else if (tid < 96) {
    int r = tid >> 4, k = tid & 15;
    int pp = (k >> 3) ? 129 : 0, c8 = k & 7;
    *reinterpret_cast<bf16x8*>((char*)As + r * 16640 + pp * 128 +
                               ((c8 ^ (pp & 7)) << 4)) = z;
  }
  __syncthreads();

  // ---- B0 via gload_lds (48 wave-issues, 3/wave; drain hides under A-stage)
#pragma unroll
  for (int k = 0; k < 3; ++k) {
    int wi = wave * 3 + k;
    gload16(AWsw + wi * 512 + lane * 8, (char*)Bs + wi * 1024);
  }

  // ---- A-stage: 6144 chunks = (r 0..5) x (px 0..127) x (c8 0..7), 6/thread
  const float* xim = x + ((long long)n * HH) * WWID * C_IN;
#pragma unroll
  for (int t = 0; t < 6; ++t) {
    int cid = t * 1024 + tid;
    int r = cid >> 10, rem = cid & 1023;
    int px = rem >> 3, c8 = rem & 7;
    int hh = h0 - 1 + r;
    if ((unsigned)hh < (unsigned)HH) {
      const float* sp = xim + (long long)hh * (WWID * C_IN) + px * C_IN + c8 * 8;
      float4 v0 = *reinterpret_cast<const float4*>(sp);
      float4 v1 = *reinterpret_cast<const float4*>(sp + 4);
      int pp = px + 1;
      *reinterpret_cast<bf16x8*>((char*)As + r * 16640 + pp * 128 +
                                 ((c8 ^ (pp & 7)) << 4)) = pack8(v0, v1);
    }
  }
  __syncthreads();

  f32x4 acc[4][4] = {};
  bf16x8 pre[3];

#define PREFETCH(SN)                                                         \
  _Pragma("unroll")                                                          \
  for (int k = 0; k < 3; ++k)                                                \
    pre[k] = *reinterpret_cast<const bf16x8*>(                               \
        AWsw + (SN) * 24576 + (k * 1024 + tid) * 8);

#define BWRITE()                                                             \
  _Pragma("unroll")                                                          \
  for (int k = 0; k < 3; ++k)                                                \
    *reinterpret_cast<bf16x8*>(Bs + (k * 1024 + tid) * 8) = pre[k];

  // one slice-phase: 3 positions (j=pl) x 2 ch x (4 b + 4 a reads + 16 MFMA)
#define COMPUTE(S)                                                           \
  __builtin_amdgcn_s_setprio(1);                                             \
  _Pragma("unroll")                                                          \
  for (int pl = 0; pl < 3; ++pl) {                                           \
    _Pragma("unroll")                                                        \
    for (int ch = 0; ch < 2; ++ch) {                                         \
      const char* bp = (const char*)Bs + pl * 16384 + (f0 << 7) + lr * 128 + \
                       (((ch * 4 + lg) ^ (lr & 7)) << 4);                    \
      bf16x8 b[4];                                                           \
      _Pragma("unroll")                                                      \
      for (int nf = 0; nf < 4; ++nf)                                         \
        b[nf] = *reinterpret_cast<const bf16x8*>(bp + nf * 2048);            \
      bf16x8 a[4];                                                           \
      _Pragma("unroll")                                                      \
      for (int mfi = 0; mfi < 4; ++mfi) {                                    \
        int pxb = m0 + mfi * 16 + lr + pl;                                   \
        a[mfi] = *reinterpret_cast<const bf16x8*>(                           \
            (const char*)As + (ro + (S)) * 16640 + pxb * 128 +               \
            (((ch * 4 + lg) ^ (pxb & 7)) << 4));                             \
      }                                                                      \
      _Pragma("unroll")                                                      \
      for (int mfi = 0; mfi < 4; ++mfi)                                      \
        _Pragma("unroll")                                                    \
        for (int nf = 0; nf < 4; ++nf)                                       \
          acc[mfi][nf] = __builtin_amdgcn_mfma_f32_16x16x32_bf16(            \
              a[mfi], b[nf], acc[mfi][nf], 0, 0, 0);                         \
    }                                                                        \
  }                                                                          \
  __builtin_amdgcn_s_setprio(0);

  PREFETCH(1)
  COMPUTE(0)
  __syncthreads();
  BWRITE()
  __syncthreads();
  PREFETCH(2)
  COMPUTE(1)
  __syncthreads();
  BWRITE()
  __syncthreads();
  COMPUTE(2)

  // ---- epilogue: f = f0+nf*16+lr, w = m0+mfi*16+lg*4+r4; nf-inner stores.
  float bi[4];
#pragma unroll
  for (int nf = 0; nf < 4; ++nf) bi[nf] = bias[f0 + nf * 16 + lr];
  int ho = h0 + ro;
  long long ob = ((long long)(n * HH + ho)) * WWID * F_OUT + f0 + lr;
#pragma unroll
  for (int mfi = 0; mfi < 4; ++mfi) {
#pragma unroll
    for (int r4 = 0; r4 < 4; ++r4) {
      int w = m0 + mfi * 16 + lg * 4 + r4;
      float* op = out + ob + (long long)w * F_OUT;
#pragma unroll
      for (int nf = 0; nf < 4; ++nf)
        op[nf * 16] = fmaxf(acc[mfi][nf][r4] + bi[nf], 0.f);
    }
  }
#undef PREFETCH
#undef BWRITE
#undef COMPUTE
}

extern "C" void kernel_launch(void* const* d_in, const int* in_sizes, int n_in,
                              void* d_out, int out_size, void* d_ws, size_t ws_size,
                              hipStream_t stream) {
  const float* x    = (const float*)d_in[0];  // (16,128,128,64)
  const float* kern = (const float*)d_in[1];  // (3,3,64,128)
  const float* bias = (const float*)d_in[2];  // (128,)
  const float* D    = (const float*)d_in[3];  // (3,3,64,128)
  const float* gu   = (const float*)d_in[4];  // (1,128,64,9)

  unsigned short* AWsw = (unsigned short*)d_ws;  // 3 slices x 48 KiB = 144 KiB

  compute_aw<<<(F_OUT * C_IN + 255) / 256, 256, 0, stream>>>(kern, D, gu, AWsw);

  conv6<<<NB * (HH / 4), 1024, 0, stream>>>(x, AWsw, bias, (float*)d_out);
}